// Round 2
// baseline (82291.656 us; speedup 1.0000x reference)
//
#include <hip/hip_runtime.h>
#include <hip/hip_cooperative_groups.h>
#include <cmath>

namespace cg = cooperative_groups;

#define SEQ   512
#define BATCH 64
#define DIN   1024
#define DH    1024

// ---------------------------------------------------------------------------
// Phase 1: x_proj = X @ W_ih^T + b_ih + b_hh  -> written into d_out[s][b][h]
// (unchanged from R1 — correct, ~1 ms; optimize later if profile says so)
// ---------------------------------------------------------------------------
__global__ __launch_bounds__(256) void proj_kernel(
    const float* __restrict__ X, const float* __restrict__ W,
    const float* __restrict__ b_ih, const float* __restrict__ b_hh,
    float* __restrict__ C) {
  __shared__ float As[64][17];
  __shared__ float Bs[64][17];
  const int m0 = blockIdx.x * 64;
  const int n0 = blockIdx.y * 64;
  const int tid = threadIdx.x;
  const int tm = tid >> 4;
  const int tn = tid & 15;
  const int lrow = tid >> 2;
  const int lk4  = (tid & 3) * 4;

  float acc[4][4];
#pragma unroll
  for (int i = 0; i < 4; ++i)
#pragma unroll
    for (int j = 0; j < 4; ++j) acc[i][j] = 0.f;

  for (int kt = 0; kt < DIN; kt += 16) {
    float4 av = *(const float4*)(X + (size_t)(m0 + lrow) * DIN + kt + lk4);
    float4 bv = *(const float4*)(W + (size_t)(n0 + lrow) * DIN + kt + lk4);
    __syncthreads();
    As[lrow][lk4 + 0] = av.x; As[lrow][lk4 + 1] = av.y;
    As[lrow][lk4 + 2] = av.z; As[lrow][lk4 + 3] = av.w;
    Bs[lrow][lk4 + 0] = bv.x; Bs[lrow][lk4 + 1] = bv.y;
    Bs[lrow][lk4 + 2] = bv.z; Bs[lrow][lk4 + 3] = bv.w;
    __syncthreads();
#pragma unroll
    for (int kk = 0; kk < 16; ++kk) {
      float a[4], b[4];
#pragma unroll
      for (int i = 0; i < 4; ++i) a[i] = As[tm * 4 + i][kk];
#pragma unroll
      for (int j = 0; j < 4; ++j) b[j] = Bs[tn * 4 + j][kk];
#pragma unroll
      for (int i = 0; i < 4; ++i)
#pragma unroll
        for (int j = 0; j < 4; ++j) acc[i][j] += a[i] * b[j];
    }
  }

#pragma unroll
  for (int j = 0; j < 4; ++j) {
    const int n = n0 + tn * 4 + j;
    const float bias = b_ih[n] + b_hh[n];
#pragma unroll
    for (int i = 0; i < 4; ++i) {
      const int m = m0 + tm * 4 + i;
      C[(size_t)m * DH + n] = acc[i][j] + bias;
    }
  }
}

// ---------------------------------------------------------------------------
// Phase 2: persistent cooperative scan.
// 256 blocks x 128 threads; block owns 4 j-rows; wave w (=tid>>6) owns
// j = j0+2w, j0+2w+1. Lane = b. h kept transposed hT[2][DH][BATCH] in ws
// (ping-pong) so the staging reads are lane-coalesced. W_hh rows are
// wave-uniform -> s_load (scalar cache). h staged through LDS in 64KB
// chunks; hs[k][b] reads are 2-way (free). Agent-scope atomics for the
// cross-XCD h exchange; grid.sync() once per step.
// ---------------------------------------------------------------------------
__global__ __launch_bounds__(128) void rnn_scan(
    float* __restrict__ out, const float* __restrict__ h0,
    const float* __restrict__ W_hh, float* __restrict__ hT) {
  __shared__ float hs[256 * 64];  // 64 KB: one k-chunk of h^T
  const int tid = threadIdx.x;
  const int b = tid & 63;
  const int wv = __builtin_amdgcn_readfirstlane(tid >> 6);  // 0 or 1, uniform
  const int j0 = blockIdx.x * 4;
  const int jA = j0 + 2 * wv;
  const float* __restrict__ wArow = W_hh + (size_t)jA * DH;
  const float* __restrict__ wBrow = wArow + DH;

  // init hT[buf 0] = h0^T for this block's 4 j rows
#pragma unroll
  for (int i = 0; i < 2; ++i) {
    int idx = tid * 2 + i;            // 0..255
    int jl = idx >> 6, bb = idx & 63;
    float v = h0[(size_t)bb * DH + (j0 + jl)];
    __hip_atomic_store(&hT[(size_t)(j0 + jl) * BATCH + bb], v,
                       __ATOMIC_RELAXED, __HIP_MEMORY_SCOPE_AGENT);
  }
  cg::this_grid().sync();

  for (int t = 0; t < SEQ; ++t) {
    const float* src = hT + (size_t)(t & 1) * DH * BATCH;
    float* dst = hT + (size_t)((t + 1) & 1) * DH * BATCH;
    float a0 = 0.f, a1 = 0.f, a2 = 0.f, a3 = 0.f;

    for (int kc = 0; kc < 4; ++kc) {
      __syncthreads();  // WAR: previous chunk fully consumed
      const float* sc = src + (size_t)kc * 256 * 64;
      // stage 64KB: 16384 floats / 128 threads = 128 each, coalesced,
      // agent-scope loads (bypass possibly-stale L1)
#pragma unroll 8
      for (int i = 0; i < 128; ++i) {
        int idx = i * 128 + tid;
        hs[idx] = __hip_atomic_load(&sc[idx], __ATOMIC_RELAXED,
                                    __HIP_MEMORY_SCOPE_AGENT);
      }
      __syncthreads();  // RAW: chunk visible

      const int kb = kc * 256;
#pragma unroll 8
      for (int k = 0; k < 256; k += 2) {
        float h0v = hs[k * 64 + b];
        float h1v = hs[(k + 1) * 64 + b];
        a0 = fmaf(wArow[kb + k], h0v, a0);
        a1 = fmaf(wBrow[kb + k], h0v, a1);
        a2 = fmaf(wArow[kb + k + 1], h1v, a2);
        a3 = fmaf(wBrow[kb + k + 1], h1v, a3);
      }
    }

    const float accA = a0 + a2;
    const float accB = a1 + a3;
    const size_t ob = ((size_t)t * BATCH + b) * DH;
    const float xA = out[ob + jA];
    const float xB = out[ob + jA + 1];
    const float vA = tanhf(xA + accA);
    const float vB = tanhf(xB + accB);
    out[ob + jA] = vA;
    out[ob + jA + 1] = vB;
    __hip_atomic_store(&dst[(size_t)jA * BATCH + b], vA,
                       __ATOMIC_RELAXED, __HIP_MEMORY_SCOPE_AGENT);
    __hip_atomic_store(&dst[(size_t)(jA + 1) * BATCH + b], vB,
                       __ATOMIC_RELAXED, __HIP_MEMORY_SCOPE_AGENT);
    if (t == SEQ - 1) {
      float* hl = out + (size_t)SEQ * BATCH * DH;
      hl[(size_t)b * DH + jA] = vA;
      hl[(size_t)b * DH + jA + 1] = vB;
    }
    cg::this_grid().sync();
  }
}

extern "C" void kernel_launch(void* const* d_in, const int* in_sizes, int n_in,
                              void* d_out, int out_size, void* d_ws,
                              size_t ws_size, hipStream_t stream) {
  const float* x    = (const float*)d_in[0];
  const float* h0   = (const float*)d_in[1];
  const float* W_ih = (const float*)d_in[2];
  const float* b_ih = (const float*)d_in[3];
  const float* W_hh = (const float*)d_in[4];
  const float* b_hh = (const float*)d_in[5];
  float* out = (float*)d_out;
  float* hT  = (float*)d_ws;  // 2 * DH * BATCH floats = 512 KB ping-pong

  // Phase 1: input projection + both biases -> d_out[s][b][h]
  hipLaunchKernelGGL(proj_kernel, dim3(512, 16), dim3(256), 0, stream,
                     x, W_ih, b_ih, b_hh, out);

  // Phase 2: persistent cooperative scan
  void* args[] = {(void*)&out, (void*)&h0, (void*)&W_hh, (void*)&hT};
  hipLaunchCooperativeKernel((const void*)rnn_scan, dim3(256), dim3(128),
                             args, 0, stream);
}

// Round 3
// 8424.512 us; speedup vs baseline: 9.7681x; 9.7681x over previous
//
#include <hip/hip_runtime.h>
#include <cmath>

#define SEQ   512
#define BATCH 64
#define DIN   1024
#define DH    1024

// ---------------------------------------------------------------------------
// Phase 1: x_proj = X @ W_ih^T + b_ih + b_hh  -> written into d_out[s][b][h]
// (unchanged; profile this round will show its share)
// ---------------------------------------------------------------------------
__global__ __launch_bounds__(256) void proj_kernel(
    const float* __restrict__ X, const float* __restrict__ W,
    const float* __restrict__ b_ih, const float* __restrict__ b_hh,
    float* __restrict__ C) {
  __shared__ float As[64][17];
  __shared__ float Bs[64][17];
  const int m0 = blockIdx.x * 64;
  const int n0 = blockIdx.y * 64;
  const int tid = threadIdx.x;
  const int tm = tid >> 4;
  const int tn = tid & 15;
  const int lrow = tid >> 2;
  const int lk4  = (tid & 3) * 4;

  float acc[4][4];
#pragma unroll
  for (int i = 0; i < 4; ++i)
#pragma unroll
    for (int j = 0; j < 4; ++j) acc[i][j] = 0.f;

  for (int kt = 0; kt < DIN; kt += 16) {
    float4 av = *(const float4*)(X + (size_t)(m0 + lrow) * DIN + kt + lk4);
    float4 bv = *(const float4*)(W + (size_t)(n0 + lrow) * DIN + kt + lk4);
    __syncthreads();
    As[lrow][lk4 + 0] = av.x; As[lrow][lk4 + 1] = av.y;
    As[lrow][lk4 + 2] = av.z; As[lrow][lk4 + 3] = av.w;
    Bs[lrow][lk4 + 0] = bv.x; Bs[lrow][lk4 + 1] = bv.y;
    Bs[lrow][lk4 + 2] = bv.z; Bs[lrow][lk4 + 3] = bv.w;
    __syncthreads();
#pragma unroll
    for (int kk = 0; kk < 16; ++kk) {
      float a[4], b[4];
#pragma unroll
      for (int i = 0; i < 4; ++i) a[i] = As[tm * 4 + i][kk];
#pragma unroll
      for (int j = 0; j < 4; ++j) b[j] = Bs[tn * 4 + j][kk];
#pragma unroll
      for (int i = 0; i < 4; ++i)
#pragma unroll
        for (int j = 0; j < 4; ++j) acc[i][j] += a[i] * b[j];
    }
  }

#pragma unroll
  for (int j = 0; j < 4; ++j) {
    const int n = n0 + tn * 4 + j;
    const float bias = b_ih[n] + b_hh[n];
#pragma unroll
    for (int i = 0; i < 4; ++i) {
      const int m = m0 + tm * 4 + i;
      C[(size_t)m * DH + n] = acc[i][j] + bias;
    }
  }
}

// ---------------------------------------------------------------------------
// h0 -> transposed quad-packed layout hT4[k>>2][b][k&3]
// (flat float4 index = k4*64 + b). Coalesced writes; one-shot cost.
// ---------------------------------------------------------------------------
__global__ __launch_bounds__(256) void transpose_h0(
    const float* __restrict__ h0, float* __restrict__ hT) {
  const int idx = blockIdx.x * 256 + threadIdx.x;  // 0..16383
  const int k4 = idx >> 6;
  const int b = idx & 63;
  float4 v = *(const float4*)(h0 + (size_t)b * DH + (k4 << 2));
  ((float4*)hT)[idx] = v;
}

// ---------------------------------------------------------------------------
// Phase 2 step: h_t[b][j] = tanh(xp[t][b][j] + sum_k W_hh[j][k]*h_{t-1}[b][k])
// Grid 128 blocks x 256 thr. Wave = (2 j-rows) x 64 b-lanes; block owns 8 j.
// h_{t-1} read from quad-packed transposed ping-pong buffer: one coalesced
// float4 per lane per 4 k. W rows wave-uniform (readfirstlane -> scalar
// path). 2 accumulators per j: dep distance = 2 instrs = 4 cyc = FMA latency.
// Writes h_t into out[t] (+h_last at t=SEQ-1) and into the other hT buffer.
// ---------------------------------------------------------------------------
__global__ __launch_bounds__(256) void rnn_step(
    const float* __restrict__ hTprev, float* __restrict__ hTnext,
    const float* __restrict__ W_hh, float* __restrict__ out, int t) {
  const int tid = threadIdx.x;
  const int b = tid & 63;
  const int wv = tid >> 6;                               // 0..3
  const int ju = __builtin_amdgcn_readfirstlane((blockIdx.x << 3) + (wv << 1));
  const float* __restrict__ w0 = W_hh + (size_t)ju * DH;
  const float* __restrict__ w1 = w0 + DH;
  const float4* __restrict__ hp = (const float4*)hTprev;  // hp[k4*64 + b]

  float a0 = 0.f, a1 = 0.f, a2 = 0.f, a3 = 0.f;
#pragma unroll 8
  for (int k4 = 0; k4 < 256; ++k4) {
    float4 hv = hp[(k4 << 6) + b];
    const int k = k4 << 2;
    a0 = fmaf(w0[k + 0], hv.x, a0);
    a1 = fmaf(w0[k + 1], hv.y, a1);
    a0 = fmaf(w0[k + 2], hv.z, a0);
    a1 = fmaf(w0[k + 3], hv.w, a1);
    a2 = fmaf(w1[k + 0], hv.x, a2);
    a3 = fmaf(w1[k + 1], hv.y, a3);
    a2 = fmaf(w1[k + 2], hv.z, a2);
    a3 = fmaf(w1[k + 3], hv.w, a3);
  }
  const float s0 = a0 + a1;
  const float s1 = a2 + a3;

  const size_t ob = ((size_t)t * BATCH + b) * DH;
  const float v0 = tanhf(out[ob + ju] + s0);
  const float v1 = tanhf(out[ob + ju + 1] + s1);
  out[ob + ju] = v0;
  out[ob + ju + 1] = v1;

  // hTnext quad-packed: flat float offset = (k4*64 + b)*4 + c with k=ju
  // ju is even -> (ju&3) in {0,2}: the two floats are contiguous.
  float* hn = hTnext + ((((size_t)(ju >> 2) << 6) + b) << 2) + (ju & 3);
  hn[0] = v0;
  hn[1] = v1;

  if (t == SEQ - 1) {
    float* hl = out + (size_t)SEQ * BATCH * DH;
    hl[(size_t)b * DH + ju] = v0;
    hl[(size_t)b * DH + ju + 1] = v1;
  }
}

extern "C" void kernel_launch(void* const* d_in, const int* in_sizes, int n_in,
                              void* d_out, int out_size, void* d_ws,
                              size_t ws_size, hipStream_t stream) {
  const float* x    = (const float*)d_in[0];
  const float* h0   = (const float*)d_in[1];
  const float* W_ih = (const float*)d_in[2];
  const float* b_ih = (const float*)d_in[3];
  const float* W_hh = (const float*)d_in[4];
  const float* b_hh = (const float*)d_in[5];
  float* out = (float*)d_out;
  float* hA = (float*)d_ws;              // 256 KB
  float* hB = hA + (size_t)DH * BATCH;   // 256 KB

  // Phase 1: input projection + both biases -> d_out[s][b][h]
  hipLaunchKernelGGL(proj_kernel, dim3(512, 16), dim3(256), 0, stream,
                     x, W_ih, b_ih, b_hh, out);

  // h0 -> transposed quad-packed buffer A
  hipLaunchKernelGGL(transpose_h0, dim3(64), dim3(256), 0, stream, h0, hA);

  // Phase 2: one launch per step, ping-pong hT buffers
  for (int t = 0; t < SEQ; ++t) {
    const float* src = (t & 1) ? hB : hA;
    float* dst = (t & 1) ? hA : hB;
    hipLaunchKernelGGL(rnn_step, dim3(128), dim3(256), 0, stream,
                       src, dst, W_hh, out, t);
  }
}